// Round 10
// baseline (4584.159 us; speedup 1.0000x reference)
//
#include <hip/hip_runtime.h>

// Round 10: k_scan2f = R9 + split accumulators (acc_a = bias + x-part kc0-3,
// acc_b = h-part kc4-7). Two independent 4-deep MFMA chains instead of one
// 8-deep chain: halves the barrier->epilogue dependent latency; MFMA becomes
// issue-bound. Epilogue sums qsel(a)+qsel(b). Everything else as R9.

typedef _Float16 f16x8  __attribute__((ext_vector_type(8)));
typedef float    f32x4  __attribute__((ext_vector_type(4)));

#define DEVI static __device__ __forceinline__

constexpr int   T1c   = 20;
constexpr int   EMBc  = 32;
constexpr int   H1c   = 64;
constexpr int   H2c   = 128;
constexpr int   LMAXc = 1024;
constexpr int   Ntot  = 24832;           // sum of lengths
constexpr int   NTc   = Ntot * T1c;      // 496640
constexpr int   R2c   = 32 * LMAXc;      // 32768
constexpr float EPSc  = 1e-5f;

DEVI float sigm(float x)   { return 1.f / (1.f + __expf(-x)); }
DEVI float tanhf_(float x) { return 1.f - 2.f / (1.f + __expf(2.f * x)); }

DEVI void barrier_lds() {                // barrier draining LDS only (not vmcnt)
    asm volatile("s_waitcnt lgkmcnt(0)\n\ts_barrier" ::: "memory");
}
DEVI void drain_vmem() {
    asm volatile("s_waitcnt vmcnt(0)" ::: "memory");
}

// ---------------- weight prep: f32 -> fp16, row stride OS, col offset KO
__global__ void __launch_bounds__(256)
k_prep16s(const float* __restrict__ in, _Float16* __restrict__ out,
          int R, int K, int OS, int KO)
{
    int i = blockIdx.x * 256 + threadIdx.x;
    if (i >= R * K) return;
    int r = i / K, k = i - r * K;
    out[(size_t)r * OS + KO + k] = (_Float16)in[i];
}

// ---------------- embedding: x = embed_w[id] * id -> fp16 seq1 (row stride 64)
__global__ void __launch_bounds__(256)
k_embed16(const int* __restrict__ atoms, const float* __restrict__ ew,
          _Float16* __restrict__ s16)
{
    int i = blockIdx.x * 256 + threadIdx.x;
    if (i >= NTc * EMBc) return;
    int nt = i / EMBc, e = i - nt * EMBc;
    int id = atoms[nt];
    s16[(size_t)nt * H1c + e] = (_Float16)(ew[id * EMBc + e] * (float)id);
}

// ---------------- LSTM1 scan, single-term fp16 (unchanged)
template <int KIN>
__global__ void __launch_bounds__(256)
k_scan1f(_Float16* seq, const _Float16* __restrict__ W16,
         const float* __restrict__ bptr, float* __restrict__ dacc,
         int accum, int writeSeq)
{
    constexpr int KTOT = KIN + 64;
    constexpr int KCH  = KTOT / 32;
    constexpr int SX   = KTOT + 8;
    __shared__ alignas(16) _Float16 xh[32 * SX];

    const int tid  = threadIdx.x;
    const int lane = tid & 63;
    const int wv   = tid >> 6;
    const int l16  = lane & 15;
    const int quad = lane >> 4;
    const int n0   = blockIdx.x * 32;
    const int d    = wv * 16 + l16;

    float bias[4];
#pragma unroll
    for (int g = 0; g < 4; ++g) bias[g] = bptr[g * 64 + d];

    f16x8 wF[KCH][4];
#pragma unroll
    for (int kc = 0; kc < KCH; ++kc) {
        const int kb = kc * 32 + quad * 8;
#pragma unroll
        for (int g = 0; g < 4; ++g)
            wF[kc][g] = *(const f16x8*)&W16[(size_t)(g * 64 + d) * 128 + kb];
    }

    f32x4 c[2];
    c[0] = {1.f, 1.f, 1.f, 1.f};
    c[1] = {1.f, 1.f, 1.f, 1.f};

#pragma unroll
    for (int mt = 0; mt < 2; ++mt)
#pragma unroll
        for (int r = 0; r < 4; ++r)
            xh[(mt * 16 + quad * 4 + r) * SX + KIN + d] = (_Float16)1.0f;

#pragma unroll 1
    for (int t = 0; t < T1c; ++t) {
        for (int idx = tid; idx < 32 * (KIN / 8); idx += 256) {
            int s = idx / (KIN / 8), k8 = idx - s * (KIN / 8);
            *(f16x8*)&xh[s * SX + k8 * 8] =
                *(const f16x8*)&seq[((size_t)(n0 + s) * T1c + t) * H1c + k8 * 8];
        }
        __syncthreads();

        f32x4 acc[2][4];
#pragma unroll
        for (int mt = 0; mt < 2; ++mt)
#pragma unroll
            for (int g = 0; g < 4; ++g)
                acc[mt][g] = {bias[g], bias[g], bias[g], bias[g]};

#pragma unroll
        for (int kc = 0; kc < KCH; ++kc) {
            const int kb = kc * 32 + quad * 8;
            f16x8 ah[2];
#pragma unroll
            for (int mt = 0; mt < 2; ++mt)
                ah[mt] = *(const f16x8*)&xh[(mt * 16 + l16) * SX + kb];
#pragma unroll
            for (int g = 0; g < 4; ++g)
#pragma unroll
                for (int mt = 0; mt < 2; ++mt)
                    acc[mt][g] = __builtin_amdgcn_mfma_f32_16x16x32_f16(ah[mt], wF[kc][g], acc[mt][g], 0, 0, 0);
        }
        __syncthreads();

#pragma unroll
        for (int mt = 0; mt < 2; ++mt)
#pragma unroll
            for (int r = 0; r < 4; ++r) {
                float iv = sigm(acc[mt][0][r]);
                float fv = sigm(acc[mt][1][r]);
                float gv = tanhf_(acc[mt][2][r]);
                float ov = sigm(acc[mt][3][r]);
                float cv = fv * c[mt][r] + iv * gv;
                c[mt][r] = cv;
                float hv = ov * tanhf_(cv);
                _Float16 hf = (_Float16)hv;
                int s = mt * 16 + quad * 4 + r;
                xh[s * SX + KIN + d] = hf;
                if (writeSeq)
                    seq[((size_t)(n0 + s) * T1c + t) * H1c + d] = hf;
                if (t == T1c - 1) {
                    int o = (n0 + s) * H1c + d;
                    float val = 0.25f * (hv + cv);
                    if (accum) dacc[o] += val; else dacc[o] = val;
                }
            }
    }
}

// ---------------- BN2 stats
__global__ void __launch_bounds__(256)
k_bn2_stats(const int* __restrict__ lens, const float* __restrict__ dacc,
            float* __restrict__ stats)
{
    int b = blockIdx.x;
    int off = 0;
    for (int i = 0; i < b; ++i) off += lens[i];
    int len = lens[b];
    const float* base = dacc + (long)off * H1c;
    float s = 0.f, ss = 0.f;
    int total = len * H1c;
    for (int i = threadIdx.x; i < total; i += 256) { float v = base[i]; s += v; ss += v * v; }
    __shared__ float rs[256], rss[256];
    rs[threadIdx.x] = s; rss[threadIdx.x] = ss;
    __syncthreads();
    for (int st = 128; st > 0; st >>= 1) {
        if (threadIdx.x < st) { rs[threadIdx.x] += rs[threadIdx.x + st]; rss[threadIdx.x] += rss[threadIdx.x + st]; }
        __syncthreads();
    }
    if (threadIdx.x == 0) {
        float m = rs[0] / (float)(LMAXc * H1c);
        float v = rss[0] / (float)(LMAXc * H1c) - m * m;
        stats[b]      = m;
        stats[32 + b] = rsqrtf(fmaxf(v, 0.f) + EPSc);
        stats[64 + b] = (float)off;
    }
}

// ---------------- BN2 apply -> LSTM2 layer-0 input, fp16, rows (t*32+b) of 128
__global__ void __launch_bounds__(256)
k_bn2_apply(const float* __restrict__ dacc, const float* __restrict__ stats,
            const int* __restrict__ lens, const float* __restrict__ g,
            const float* __restrict__ bb, _Float16* __restrict__ outA)
{
    int i = blockIdx.x * 256 + threadIdx.x;
    if (i >= R2c * 128) return;
    int rr = i >> 7, k = i & 127;
    int b = rr >> 10, p = rr & 1023;
    float y = 0.f;
    if (k < H1c) {
        int off = (int)stats[64 + b];
        float x = (p < lens[b]) ? dacc[(off + p) * H1c + k] : 0.f;
        y = (x - stats[b]) * stats[32 + b] * g[b] + bb[b];
    }
    outA[(size_t)(p * 32 + b) * 128 + k] = (_Float16)y;
}

DEVI float qsel(f32x4 a, int quad) {     // a[quad] via cndmask
    float t01 = (quad & 1) ? a[1] : a[0];
    float t23 = (quad & 1) ? a[3] : a[2];
    return (quad & 2) ? t23 : t01;
}

// ---------------- LSTM2: 8 WGs x 4 samples, 4 layer passes serial per WG.
// 512 thr = 8 waves (2/SIMD). Wave w owns cells [w*16,w*16+16). SH=272:
// 2-way-free LDS. Split accumulators: acc_a = bias + x-part (kc0-3),
// acc_b = h-part (kc4-7) -> two independent 4-deep MFMA chains. LDS-only
// barrier per step; vmcnt drain only at pass boundaries.
__global__ void __launch_bounds__(512, 2)
k_scan2f(const _Float16* __restrict__ seqA,   // (t*32+b) rows x 128 halves
         const _Float16* __restrict__ wcomb,  // [4][512][256] fp16
         const float* __restrict__ b0, const float* __restrict__ bS,
         _Float16* __restrict__ hseq,         // [8 WG][2][1024*4*128] ping-pong
         float* __restrict__ c2)              // [4][32][128]
{
    constexpr int SH = 272;
    __shared__ alignas(16) _Float16 av[2][4 * SH];

    const int S0   = blockIdx.x * 4;
    const int tid  = threadIdx.x;
    const int lane = tid & 63;
    const int w    = tid >> 6;                // wave 0..7
    const int l16  = lane & 15, quad = lane >> 4;
    const int cell = w * 16 + l16;            // 0..127

    _Float16* hbufA = hseq + (size_t)blockIdx.x * 2 * LMAXc * 4 * 128;
    _Float16* hbufB = hbufA + (size_t)LMAXc * 4 * 128;

#pragma unroll 1
    for (int l = 0; l < 4; ++l) {
        const _Float16* W  = wcomb + (size_t)l * 512 * 256;
        const float*    bp = (l == 0) ? b0 : bS + (l - 1) * 512;
        const _Float16* xsrc;  int xstride;
        if (l == 0) { xsrc = seqA + (size_t)S0 * 128; xstride = 32 * 128; }
        else        { xsrc = (l & 1) ? hbufA : hbufB; xstride = 4 * 128; }
        _Float16* hdst = (l & 1) ? hbufB : hbufA;

        // weights: 4 gate-tiles x 8 k-chunks = 128 VGPRs (AGPR-able)
        f16x8 wB[4][8];
#pragma unroll
        for (int g = 0; g < 4; ++g)
#pragma unroll
            for (int kc = 0; kc < 8; ++kc)
                wB[g][kc] = *(const f16x8*)&W[(size_t)(g * 128 + cell) * 256 + kc * 32 + quad * 8];

        float bias[4];
#pragma unroll
        for (int g = 0; g < 4; ++g) bias[g] = bp[g * 128 + cell];

        float cst = 1.f;

        // ---- pass boundary: drain own global stores, full barrier, fence
        drain_vmem();
        __syncthreads();
        __threadfence();
        // init parity 1: h(t=-1)=1; x(0) staged by waves 0-3 (sample = w)
        av[1][quad * SH + 128 + cell] = (_Float16)1.0f;
        if (w < 4 && lane < 16)
            *(f16x8*)&av[1][w * SH + lane * 8] =
                *(const f16x8*)&xsrc[(size_t)w * 128 + lane * 8];
        __syncthreads();

#pragma unroll 1
        for (int t = 0; t < LMAXc; ++t) {
            const int pw = t & 1, pr = pw ^ 1;

            f16x8 xn;
            const bool doStage = (w < 4) && (lane < 16) && (t + 1 < LMAXc);
            if (doStage)
                xn = *(const f16x8*)&xsrc[(size_t)(t + 1) * xstride + w * 128 + lane * 8];

            f16x8 af[8];
#pragma unroll
            for (int kc = 0; kc < 8; ++kc)
                af[kc] = *(const f16x8*)&av[pr][(l16 & 3) * SH + kc * 32 + quad * 8];

            // split accumulators: a = bias + x-part (kc0-3), b = h-part (kc4-7)
            f32x4 acc_a[4], acc_b[4];
#pragma unroll
            for (int g = 0; g < 4; ++g) {
                const float bv = bias[g];
                acc_a[g] = {bv, bv, bv, bv};
                acc_b[g] = {0.f, 0.f, 0.f, 0.f};
            }
#pragma unroll
            for (int kc = 0; kc < 4; ++kc) {
#pragma unroll
                for (int g = 0; g < 4; ++g)
                    acc_a[g] = __builtin_amdgcn_mfma_f32_16x16x32_f16(af[kc], wB[g][kc], acc_a[g], 0, 0, 0);
#pragma unroll
                for (int g = 0; g < 4; ++g)
                    acc_b[g] = __builtin_amdgcn_mfma_f32_16x16x32_f16(af[kc + 4], wB[g][kc + 4], acc_b[g], 0, 0, 0);
            }

            // epilogue: this lane = (cell, sample=quad)
            float gi = qsel(acc_a[0], quad) + qsel(acc_b[0], quad);
            float gf = qsel(acc_a[1], quad) + qsel(acc_b[1], quad);
            float gg = qsel(acc_a[2], quad) + qsel(acc_b[2], quad);
            float go = qsel(acc_a[3], quad) + qsel(acc_b[3], quad);
            float cv = sigm(gf) * cst + sigm(gi) * tanhf_(gg);
            cst = cv;
            float hv = sigm(go) * tanhf_(cv);
            _Float16 hf = (_Float16)hv;
            av[pw][quad * SH + 128 + cell] = hf;
            if (l < 3) hdst[(size_t)(t * 4 + quad) * 128 + cell] = hf;  // floats past barrier
            if (t == LMAXc - 1)
                c2[(size_t)(l * 32 + S0 + quad) * 128 + cell] = 0.25f * cv;

            if (doStage)
                *(f16x8*)&av[pw][w * SH + lane * 8] = xn;
            barrier_lds();                      // LDS-only drain + barrier
        }
    }
}

// ---------------- head: BN3 + MLP + relu(sum), single WG fp32
DEVI void bn_rows_dev(float* X, int K, const float* g, const float* bb,
                      float* mv, int tid)
{
    __syncthreads();
    if (tid < 32) {
        float s = 0.f, ss = 0.f;
        const float* r = X + tid * K;
        for (int k = 0; k < K; ++k) { float v = r[k]; s += v; ss += v * v; }
        float m = s / (float)K;
        float vv = ss / (float)K - m * m;
        mv[tid]      = m;
        mv[32 + tid] = rsqrtf(fmaxf(vv, 0.f) + EPSc);
    }
    __syncthreads();
    for (int i = tid; i < 32 * K; i += 256) {
        int b = i / K;
        X[i] = (X[i] - mv[b]) * mv[32 + b] * g[b] + bb[b];
    }
    __syncthreads();
}

DEVI void lin_dev(const float* X, int K, const float* W, const float* bias,
                  int NO, float* Y, int relu, int tid)
{
    __syncthreads();
    for (int i = tid; i < 32 * NO; i += 256) {
        int b = i / NO, j = i - b * NO;
        float a = bias[j];
        const float* xr = X + b * K;
        const float* wr = W + j * K;
        for (int k = 0; k < K; ++k) a += xr[k] * wr[k];
        Y[i] = relu ? fmaxf(a, 0.f) : a;
    }
    __syncthreads();
}

__global__ void __launch_bounds__(256)
k_head(const float* __restrict__ c2, const float* __restrict__ g3, const float* __restrict__ bb3,
       const float* w1, const float* b1, const float* w2, const float* b2,
       const float* w22, const float* b22, const float* w3, const float* b3,
       const float* w4, const float* b4, const float* w5, const float* b5,
       float* __restrict__ out)
{
    __shared__ float A[32 * 128];
    __shared__ float Bf[32 * 128];
    __shared__ float mv[64];
    const int tid = threadIdx.x;

    for (int i = tid; i < 32 * 128; i += 256)
        A[i] = c2[i] + c2[4096 + i] + c2[8192 + i] + c2[12288 + i];
    bn_rows_dev(A, 128, g3, bb3, mv, tid);
    lin_dev(A, 128, w1, b1, 128, Bf, 1, tid);
    lin_dev(Bf, 128, w2, b2, 64, A, 1, tid);
    bn_rows_dev(A, 64, g3, bb3, mv, tid);
    lin_dev(A, 64, w22, b22, 64, Bf, 1, tid);
    lin_dev(Bf, 64, w3, b3, 32, A, 1, tid);
    lin_dev(A, 32, w4, b4, 32, Bf, 1, tid);
    lin_dev(Bf, 32, w5, b5, 16, A, 0, tid);
    if (tid < 32) {
        float s = 0.f;
        for (int j = 0; j < 16; ++j) s += A[tid * 16 + j];
        out[tid] = fmaxf(s, 0.f);
    }
}

// ---------------- host
extern "C" void kernel_launch(void* const* d_in, const int* in_sizes, int n_in,
                              void* d_out, int out_size, void* d_ws, size_t ws_size,
                              hipStream_t stream)
{
    const int*   atoms  = (const int*)d_in[0];
    const int*   lens   = (const int*)d_in[2];
    const float* embw   = (const float*)d_in[5];
    const float* l1Wih0 = (const float*)d_in[6];
    const float* l1Whh0 = (const float*)d_in[7];
    const float* l1b0   = (const float*)d_in[8];
    const float* l1Wih  = (const float*)d_in[9];
    const float* l1Whh  = (const float*)d_in[10];
    const float* l1b    = (const float*)d_in[11];
    const float* l2Wih0 = (const float*)d_in[12];
    const float* l2Whh0 = (const float*)d_in[13];
    const float* l2b0   = (const float*)d_in[14];
    const float* l2Wih  = (const float*)d_in[15];
    const float* l2Whh  = (const float*)d_in[16];
    const float* l2b    = (const float*)d_in[17];
    const float* bn2g   = (const float*)d_in[18];
    const float* bn2b   = (const float*)d_in[19];
    const float* bn3g   = (const float*)d_in[20];
    const float* bn3b   = (const float*)d_in[21];
    const float* w1  = (const float*)d_in[22]; const float* b1  = (const float*)d_in[23];
    const float* w2  = (const float*)d_in[24]; const float* b2  = (const float*)d_in[25];
    const float* w22 = (const float*)d_in[26]; const float* b22 = (const float*)d_in[27];
    const float* w3  = (const float*)d_in[28]; const float* b3  = (const float*)d_in[29];
    const float* w4  = (const float*)d_in[30]; const float* b4  = (const float*)d_in[31];
    const float* w5  = (const float*)d_in[32]; const float* b5  = (const float*)d_in[33];
    float* out = (float*)d_out;

    char* base = (char*)d_ws;
    size_t off = 0;
    auto take = [&](size_t bytes) -> char* {
        char* p = base + off;
        off = (off + bytes + 255) & ~(size_t)255;
        return p;
    };
    _Float16* seq1f  = (_Float16*)take((size_t)NTc * H1c * 2);               // 63.6 MB
    float*    dacc   = (float*)take((size_t)Ntot * H1c * 4);                 // 6.4 MB
    _Float16* wcomb1 = (_Float16*)take((size_t)4 * 256 * 128 * 2);           // 256 KB
    _Float16* wcomb  = (_Float16*)take((size_t)4 * 512 * 256 * 2);           // 1 MB
    _Float16* seqA   = (_Float16*)take((size_t)R2c * 128 * 2);               // 8.4 MB
    _Float16* hseq   = (_Float16*)take((size_t)8 * 2 * LMAXc * 4 * 128 * 2); // 16.8 MB
    float*    stats  = (float*)take(1024);
    float*    c2     = (float*)take((size_t)4 * 32 * 128 * 4);

    auto prep16 = [&](const float* src, _Float16* dst, int R, int K, int OS, int KO) {
        int n = R * K;
        k_prep16s<<<(n + 255) / 256, 256, 0, stream>>>(src, dst, R, K, OS, KO);
    };

    // LSTM1 combined fp16 [Wih | Whh], row stride 128
    prep16(l1Wih0, wcomb1, 256, 32, 128, 0);
    prep16(l1Whh0, wcomb1, 256, 64, 128, 32);
    for (int l = 1; l < 4; ++l) {
        prep16(l1Wih + (l - 1) * 256 * 64, wcomb1 + (size_t)l * 256 * 128, 256, 64, 128, 0);
        prep16(l1Whh + (l - 1) * 256 * 64, wcomb1 + (size_t)l * 256 * 128, 256, 64, 128, 64);
    }
    // LSTM2 combined fp16 [Wih (zero-padded to 128) | Whh], row stride 256
    hipMemsetAsync(wcomb, 0, (size_t)4 * 512 * 256 * 2, stream);
    prep16(l2Wih0, wcomb, 512, 64, 256, 0);
    prep16(l2Whh0, wcomb, 512, 128, 256, 128);
    for (int l = 1; l < 4; ++l) {
        prep16(l2Wih + (l - 1) * 512 * 128, wcomb + (size_t)l * 512 * 256, 512, 128, 256, 0);
        prep16(l2Whh + (l - 1) * 512 * 128, wcomb + (size_t)l * 512 * 256, 512, 128, 256, 128);
    }

    k_embed16<<<(NTc * EMBc + 255) / 256, 256, 0, stream>>>(atoms, embw, seq1f);

    for (int l = 0; l < 4; ++l) {
        const float* bp = (l == 0) ? l1b0 : l1b + (l - 1) * 256;
        if (l == 0)
            k_scan1f<32><<<Ntot / 32, 256, 0, stream>>>(seq1f, wcomb1, bp, dacc, 0, 1);
        else
            k_scan1f<64><<<Ntot / 32, 256, 0, stream>>>(seq1f, wcomb1 + (size_t)l * 256 * 128,
                                                        bp, dacc, 1, (l != 3) ? 1 : 0);
    }

    k_bn2_stats<<<32, 256, 0, stream>>>(lens, dacc, stats);
    k_bn2_apply<<<(R2c * 128 + 255) / 256, 256, 0, stream>>>(dacc, stats, lens, bn2g, bn2b, seqA);

    k_scan2f<<<8, 512, 0, stream>>>(seqA, wcomb, l2b0, l2b, hseq, c2);

    k_head<<<1, 256, 0, stream>>>(c2, bn3g, bn3b, w1, b1, w2, b2, w22, b22,
                                  w3, b3, w4, b4, w5, b5, out);

    (void)in_sizes; (void)n_in; (void)out_size; (void)ws_size;
}

// Round 11
// 4082.339 us; speedup vs baseline: 1.1229x; 1.1229x over previous
//
#include <hip/hip_runtime.h>

// Round 11: LSTM2 x-path hoisted out of the scan.
//  Per pass l (serial layers -> separate kernels, coherence via stream order):
//   1) k_xg: GEMM  xg[t*32+s][cell*4+g] = bias + Wih_l . x  (parallel, 1024 WGs)
//   2) k_scan2g: recurrence only (K=128 h-path, 16 MFMA/wave/step, LDS h-only
//      SH=144 -> 2-way-free banks, no fences, xg float4 reg-double-buffered).
//  R10's split-acc reverted (measured neutral). LSTM1 fp16 unchanged.

typedef _Float16 f16x8  __attribute__((ext_vector_type(8)));
typedef float    f32x4  __attribute__((ext_vector_type(4)));

#define DEVI static __device__ __forceinline__

constexpr int   T1c   = 20;
constexpr int   EMBc  = 32;
constexpr int   H1c   = 64;
constexpr int   H2c   = 128;
constexpr int   LMAXc = 1024;
constexpr int   Ntot  = 24832;           // sum of lengths
constexpr int   NTc   = Ntot * T1c;      // 496640
constexpr int   R2c   = 32 * LMAXc;      // 32768
constexpr float EPSc  = 1e-5f;

DEVI float sigm(float x)   { return 1.f / (1.f + __expf(-x)); }
DEVI float tanhf_(float x) { return 1.f - 2.f / (1.f + __expf(2.f * x)); }

DEVI void barrier_lds() {                // barrier draining LDS only (not vmcnt)
    asm volatile("s_waitcnt lgkmcnt(0)\n\ts_barrier" ::: "memory");
}

// ---------------- weight prep: f32 -> fp16, row stride OS, col offset KO
__global__ void __launch_bounds__(256)
k_prep16s(const float* __restrict__ in, _Float16* __restrict__ out,
          int R, int K, int OS, int KO)
{
    int i = blockIdx.x * 256 + threadIdx.x;
    if (i >= R * K) return;
    int r = i / K, k = i - r * K;
    out[(size_t)r * OS + KO + k] = (_Float16)in[i];
}

// ---------------- embedding: x = embed_w[id] * id -> fp16 seq1 (row stride 64)
__global__ void __launch_bounds__(256)
k_embed16(const int* __restrict__ atoms, const float* __restrict__ ew,
          _Float16* __restrict__ s16)
{
    int i = blockIdx.x * 256 + threadIdx.x;
    if (i >= NTc * EMBc) return;
    int nt = i / EMBc, e = i - nt * EMBc;
    int id = atoms[nt];
    s16[(size_t)nt * H1c + e] = (_Float16)(ew[id * EMBc + e] * (float)id);
}

// ---------------- LSTM1 scan, single-term fp16 (unchanged from R9)
template <int KIN>
__global__ void __launch_bounds__(256)
k_scan1f(_Float16* seq, const _Float16* __restrict__ W16,
         const float* __restrict__ bptr, float* __restrict__ dacc,
         int accum, int writeSeq)
{
    constexpr int KTOT = KIN + 64;
    constexpr int KCH  = KTOT / 32;
    constexpr int SX   = KTOT + 8;
    __shared__ alignas(16) _Float16 xh[32 * SX];

    const int tid  = threadIdx.x;
    const int lane = tid & 63;
    const int wv   = tid >> 6;
    const int l16  = lane & 15;
    const int quad = lane >> 4;
    const int n0   = blockIdx.x * 32;
    const int d    = wv * 16 + l16;

    float bias[4];
#pragma unroll
    for (int g = 0; g < 4; ++g) bias[g] = bptr[g * 64 + d];

    f16x8 wF[KCH][4];
#pragma unroll
    for (int kc = 0; kc < KCH; ++kc) {
        const int kb = kc * 32 + quad * 8;
#pragma unroll
        for (int g = 0; g < 4; ++g)
            wF[kc][g] = *(const f16x8*)&W16[(size_t)(g * 64 + d) * 128 + kb];
    }

    f32x4 c[2];
    c[0] = {1.f, 1.f, 1.f, 1.f};
    c[1] = {1.f, 1.f, 1.f, 1.f};

#pragma unroll
    for (int mt = 0; mt < 2; ++mt)
#pragma unroll
        for (int r = 0; r < 4; ++r)
            xh[(mt * 16 + quad * 4 + r) * SX + KIN + d] = (_Float16)1.0f;

#pragma unroll 1
    for (int t = 0; t < T1c; ++t) {
        for (int idx = tid; idx < 32 * (KIN / 8); idx += 256) {
            int s = idx / (KIN / 8), k8 = idx - s * (KIN / 8);
            *(f16x8*)&xh[s * SX + k8 * 8] =
                *(const f16x8*)&seq[((size_t)(n0 + s) * T1c + t) * H1c + k8 * 8];
        }
        __syncthreads();

        f32x4 acc[2][4];
#pragma unroll
        for (int mt = 0; mt < 2; ++mt)
#pragma unroll
            for (int g = 0; g < 4; ++g)
                acc[mt][g] = {bias[g], bias[g], bias[g], bias[g]};

#pragma unroll
        for (int kc = 0; kc < KCH; ++kc) {
            const int kb = kc * 32 + quad * 8;
            f16x8 ah[2];
#pragma unroll
            for (int mt = 0; mt < 2; ++mt)
                ah[mt] = *(const f16x8*)&xh[(mt * 16 + l16) * SX + kb];
#pragma unroll
            for (int g = 0; g < 4; ++g)
#pragma unroll
                for (int mt = 0; mt < 2; ++mt)
                    acc[mt][g] = __builtin_amdgcn_mfma_f32_16x16x32_f16(ah[mt], wF[kc][g], acc[mt][g], 0, 0, 0);
        }
        __syncthreads();

#pragma unroll
        for (int mt = 0; mt < 2; ++mt)
#pragma unroll
            for (int r = 0; r < 4; ++r) {
                float iv = sigm(acc[mt][0][r]);
                float fv = sigm(acc[mt][1][r]);
                float gv = tanhf_(acc[mt][2][r]);
                float ov = sigm(acc[mt][3][r]);
                float cv = fv * c[mt][r] + iv * gv;
                c[mt][r] = cv;
                float hv = ov * tanhf_(cv);
                _Float16 hf = (_Float16)hv;
                int s = mt * 16 + quad * 4 + r;
                xh[s * SX + KIN + d] = hf;
                if (writeSeq)
                    seq[((size_t)(n0 + s) * T1c + t) * H1c + d] = hf;
                if (t == T1c - 1) {
                    int o = (n0 + s) * H1c + d;
                    float val = 0.25f * (hv + cv);
                    if (accum) dacc[o] += val; else dacc[o] = val;
                }
            }
    }
}

// ---------------- BN2 stats
__global__ void __launch_bounds__(256)
k_bn2_stats(const int* __restrict__ lens, const float* __restrict__ dacc,
            float* __restrict__ stats)
{
    int b = blockIdx.x;
    int off = 0;
    for (int i = 0; i < b; ++i) off += lens[i];
    int len = lens[b];
    const float* base = dacc + (long)off * H1c;
    float s = 0.f, ss = 0.f;
    int total = len * H1c;
    for (int i = threadIdx.x; i < total; i += 256) { float v = base[i]; s += v; ss += v * v; }
    __shared__ float rs[256], rss[256];
    rs[threadIdx.x] = s; rss[threadIdx.x] = ss;
    __syncthreads();
    for (int st = 128; st > 0; st >>= 1) {
        if (threadIdx.x < st) { rs[threadIdx.x] += rs[threadIdx.x + st]; rss[threadIdx.x] += rss[threadIdx.x + st]; }
        __syncthreads();
    }
    if (threadIdx.x == 0) {
        float m = rs[0] / (float)(LMAXc * H1c);
        float v = rss[0] / (float)(LMAXc * H1c) - m * m;
        stats[b]      = m;
        stats[32 + b] = rsqrtf(fmaxf(v, 0.f) + EPSc);
        stats[64 + b] = (float)off;
    }
}

// ---------------- BN2 apply -> LSTM2 layer-0 input, fp16, rows (t*32+b) of 128
__global__ void __launch_bounds__(256)
k_bn2_apply(const float* __restrict__ dacc, const float* __restrict__ stats,
            const int* __restrict__ lens, const float* __restrict__ g,
            const float* __restrict__ bb, _Float16* __restrict__ outA)
{
    int i = blockIdx.x * 256 + threadIdx.x;
    if (i >= R2c * 128) return;
    int rr = i >> 7, k = i & 127;
    int b = rr >> 10, p = rr & 1023;
    float y = 0.f;
    if (k < H1c) {
        int off = (int)stats[64 + b];
        float x = (p < lens[b]) ? dacc[(off + p) * H1c + k] : 0.f;
        y = (x - stats[b]) * stats[32 + b] * g[b] + bb[b];
    }
    outA[(size_t)(p * 32 + b) * 128 + k] = (_Float16)y;
}

// ---------------- xg GEMM: xg[row][cell*4+g] = bias[g*128+cell] + Wih.x[row]
// rows = t*32+s, 32 rows/WG, 4 waves x 128 cols, K=128.
__global__ void __launch_bounds__(256)
k_xg(const _Float16* __restrict__ in,     // [32768][128] fp16
     const _Float16* __restrict__ Wih,    // [512][128] fp16 (gate-major rows)
     const float* __restrict__ bias,      // [512] gate-major
     float* __restrict__ xg)              // [32768][512] permuted [row][cell][g]
{
    constexpr int SX = 136;
    __shared__ alignas(16) _Float16 a[32 * SX];
    const int tid = threadIdx.x, lane = tid & 63, wv = tid >> 6;
    const int l16 = lane & 15, quad = lane >> 4;
    const int r0  = blockIdx.x * 32;

    for (int idx = tid; idx < 32 * 16; idx += 256) {
        int s = idx >> 4, k8 = idx & 15;
        *(f16x8*)&a[s * SX + k8 * 8] =
            *(const f16x8*)&in[(size_t)(r0 + s) * 128 + k8 * 8];
    }
    __syncthreads();

    f32x4 acc[2][8];
#pragma unroll
    for (int mt = 0; mt < 2; ++mt)
#pragma unroll
        for (int nt = 0; nt < 8; ++nt) {
            float bv = bias[wv * 128 + nt * 16 + l16];
            acc[mt][nt] = {bv, bv, bv, bv};
        }

#pragma unroll
    for (int kc = 0; kc < 4; ++kc) {
        const int kb = kc * 32 + quad * 8;
        f16x8 ah[2];
#pragma unroll
        for (int mt = 0; mt < 2; ++mt)
            ah[mt] = *(const f16x8*)&a[(mt * 16 + l16) * SX + kb];
#pragma unroll
        for (int nt = 0; nt < 8; ++nt) {
            f16x8 bh = *(const f16x8*)&Wih[(size_t)(wv * 128 + nt * 16 + l16) * 128 + kb];
#pragma unroll
            for (int mt = 0; mt < 2; ++mt)
                acc[mt][nt] = __builtin_amdgcn_mfma_f32_16x16x32_f16(ah[mt], bh, acc[mt][nt], 0, 0, 0);
        }
    }
#pragma unroll
    for (int mt = 0; mt < 2; ++mt)
#pragma unroll
        for (int nt = 0; nt < 8; ++nt) {
            const int col  = wv * 128 + nt * 16 + l16;
            const int gg   = col >> 7, cell = col & 127;
#pragma unroll
            for (int r = 0; r < 4; ++r) {
                int row = r0 + mt * 16 + quad * 4 + r;
                xg[(size_t)row * 512 + cell * 4 + gg] = acc[mt][nt][r];
            }
        }
}

DEVI float qsel(f32x4 a, int quad) {     // a[quad] via cndmask
    float t01 = (quad & 1) ? a[1] : a[0];
    float t23 = (quad & 1) ? a[3] : a[2];
    return (quad & 2) ? t23 : t01;
}

// ---------------- LSTM2 recurrence-only scan (one layer per launch).
// 8 WGs x 4 samples; 512 thr = 8 waves (2/SIMD). Wave w owns cells
// [w*16,w*16+16); K=128 (h only) -> 16 MFMA/wave/step, 4 ds_read_b128.
// LDS h-only, SH=144 (72 dw == 8 mod 32 -> exact 2-way = free). xg float4
// register double-buffered. No fences (kernel boundary = coherence).
__global__ void __launch_bounds__(512, 2)
k_scan2g(const float* __restrict__ xg,        // [32768][512] [row][cell][g]
         const _Float16* __restrict__ Whh,    // [512][128] fp16
         _Float16* __restrict__ hdst,         // layer h out (t*32+s rows) or unused
         float* __restrict__ c2out,           // [32][128] this layer
         int writeH)
{
    constexpr int SH = 144;
    __shared__ alignas(16) _Float16 av[2][4 * SH];

    const int S0   = blockIdx.x * 4;
    const int tid  = threadIdx.x;
    const int lane = tid & 63;
    const int w    = tid >> 6;                // wave 0..7
    const int l16  = lane & 15, quad = lane >> 4;
    const int cell = w * 16 + l16;            // 0..127

    // weights: 4 gate-tiles x 4 k-chunks = 64 VGPRs
    f16x8 wB[4][4];
#pragma unroll
    for (int g = 0; g < 4; ++g)
#pragma unroll
        for (int kc = 0; kc < 4; ++kc)
            wB[g][kc] = *(const f16x8*)&Whh[(size_t)(g * 128 + cell) * 128 + kc * 32 + quad * 8];

    const f32x4* xg4 = (const f32x4*)xg;      // index: row*128 + cell
    const int myrow0 = S0 + quad;             // sample row offset

    float cst = 1.f;
    av[1][quad * SH + cell] = (_Float16)1.0f; // h(t=-1) = 1, parity 1
    f32x4 xcur = xg4[(size_t)myrow0 * 128 + cell];
    __syncthreads();

#pragma unroll 1
    for (int t = 0; t < LMAXc; ++t) {
        const int pw = t & 1, pr = pw ^ 1;

        f32x4 xnxt;
        if (t + 1 < LMAXc)
            xnxt = xg4[(size_t)((t + 1) * 32 + myrow0) * 128 + cell];

        f16x8 af[4];
#pragma unroll
        for (int kc = 0; kc < 4; ++kc)
            af[kc] = *(const f16x8*)&av[pr][(l16 & 3) * SH + kc * 32 + quad * 8];

        f32x4 acc[4];
#pragma unroll
        for (int g = 0; g < 4; ++g) acc[g] = {0.f, 0.f, 0.f, 0.f};
#pragma unroll
        for (int kc = 0; kc < 4; ++kc)
#pragma unroll
            for (int g = 0; g < 4; ++g)
                acc[g] = __builtin_amdgcn_mfma_f32_16x16x32_f16(af[kc], wB[g][kc], acc[g], 0, 0, 0);

        // epilogue: this lane = (cell, sample=quad)
        float gi = qsel(acc[0], quad) + xcur[0];
        float gf = qsel(acc[1], quad) + xcur[1];
        float gg = qsel(acc[2], quad) + xcur[2];
        float go = qsel(acc[3], quad) + xcur[3];
        float cv = sigm(gf) * cst + sigm(gi) * tanhf_(gg);
        cst = cv;
        float hv = sigm(go) * tanhf_(cv);
        _Float16 hf = (_Float16)hv;
        av[pw][quad * SH + cell] = hf;
        if (writeH) hdst[(size_t)(t * 32 + myrow0) * 128 + cell] = hf;
        if (t == LMAXc - 1)
            c2out[(size_t)myrow0 * 128 + cell] = 0.25f * cv;

        xcur = xnxt;
        barrier_lds();
    }
}

// ---------------- head: BN3 + MLP + relu(sum), single WG fp32
DEVI void bn_rows_dev(float* X, int K, const float* g, const float* bb,
                      float* mv, int tid)
{
    __syncthreads();
    if (tid < 32) {
        float s = 0.f, ss = 0.f;
        const float* r = X + tid * K;
        for (int k = 0; k < K; ++k) { float v = r[k]; s += v; ss += v * v; }
        float m = s / (float)K;
        float vv = ss / (float)K - m * m;
        mv[tid]      = m;
        mv[32 + tid] = rsqrtf(fmaxf(vv, 0.f) + EPSc);
    }
    __syncthreads();
    for (int i = tid; i < 32 * K; i += 256) {
        int b = i / K;
        X[i] = (X[i] - mv[b]) * mv[32 + b] * g[b] + bb[b];
    }
    __syncthreads();
}

DEVI void lin_dev(const float* X, int K, const float* W, const float* bias,
                  int NO, float* Y, int relu, int tid)
{
    __syncthreads();
    for (int i = tid; i < 32 * NO; i += 256) {
        int b = i / NO, j = i - b * NO;
        float a = bias[j];
        const float* xr = X + b * K;
        const float* wr = W + j * K;
        for (int k = 0; k < K; ++k) a += xr[k] * wr[k];
        Y[i] = relu ? fmaxf(a, 0.f) : a;
    }
    __syncthreads();
}

__global__ void __launch_bounds__(256)
k_head(const float* __restrict__ c2, const float* __restrict__ g3, const float* __restrict__ bb3,
       const float* w1, const float* b1, const float* w2, const float* b2,
       const float* w22, const float* b22, const float* w3, const float* b3,
       const float* w4, const float* b4, const float* w5, const float* b5,
       float* __restrict__ out)
{
    __shared__ float A[32 * 128];
    __shared__ float Bf[32 * 128];
    __shared__ float mv[64];
    const int tid = threadIdx.x;

    for (int i = tid; i < 32 * 128; i += 256)
        A[i] = c2[i] + c2[4096 + i] + c2[8192 + i] + c2[12288 + i];
    bn_rows_dev(A, 128, g3, bb3, mv, tid);
    lin_dev(A, 128, w1, b1, 128, Bf, 1, tid);
    lin_dev(Bf, 128, w2, b2, 64, A, 1, tid);
    bn_rows_dev(A, 64, g3, bb3, mv, tid);
    lin_dev(A, 64, w22, b22, 64, Bf, 1, tid);
    lin_dev(Bf, 64, w3, b3, 32, A, 1, tid);
    lin_dev(A, 32, w4, b4, 32, Bf, 1, tid);
    lin_dev(Bf, 32, w5, b5, 16, A, 0, tid);
    if (tid < 32) {
        float s = 0.f;
        for (int j = 0; j < 16; ++j) s += A[tid * 16 + j];
        out[tid] = fmaxf(s, 0.f);
    }
}

// ---------------- host
extern "C" void kernel_launch(void* const* d_in, const int* in_sizes, int n_in,
                              void* d_out, int out_size, void* d_ws, size_t ws_size,
                              hipStream_t stream)
{
    const int*   atoms  = (const int*)d_in[0];
    const int*   lens   = (const int*)d_in[2];
    const float* embw   = (const float*)d_in[5];
    const float* l1Wih0 = (const float*)d_in[6];
    const float* l1Whh0 = (const float*)d_in[7];
    const float* l1b0   = (const float*)d_in[8];
    const float* l1Wih  = (const float*)d_in[9];
    const float* l1Whh  = (const float*)d_in[10];
    const float* l1b    = (const float*)d_in[11];
    const float* l2Wih0 = (const float*)d_in[12];
    const float* l2Whh0 = (const float*)d_in[13];
    const float* l2b0   = (const float*)d_in[14];
    const float* l2Wih  = (const float*)d_in[15];
    const float* l2Whh  = (const float*)d_in[16];
    const float* l2b    = (const float*)d_in[17];
    const float* bn2g   = (const float*)d_in[18];
    const float* bn2b   = (const float*)d_in[19];
    const float* bn3g   = (const float*)d_in[20];
    const float* bn3b   = (const float*)d_in[21];
    const float* w1  = (const float*)d_in[22]; const float* b1  = (const float*)d_in[23];
    const float* w2  = (const float*)d_in[24]; const float* b2  = (const float*)d_in[25];
    const float* w22 = (const float*)d_in[26]; const float* b22 = (const float*)d_in[27];
    const float* w3  = (const float*)d_in[28]; const float* b3  = (const float*)d_in[29];
    const float* w4  = (const float*)d_in[30]; const float* b4  = (const float*)d_in[31];
    const float* w5  = (const float*)d_in[32]; const float* b5  = (const float*)d_in[33];
    float* out = (float*)d_out;

    char* base = (char*)d_ws;
    size_t off = 0;
    auto take = [&](size_t bytes) -> char* {
        char* p = base + off;
        off = (off + bytes + 255) & ~(size_t)255;
        return p;
    };
    _Float16* seq1f  = (_Float16*)take((size_t)NTc * H1c * 2);               // 63.6 MB
    float*    dacc   = (float*)take((size_t)Ntot * H1c * 4);                 // 6.4 MB
    _Float16* wcomb1 = (_Float16*)take((size_t)4 * 256 * 128 * 2);           // 256 KB
    _Float16* wih16  = (_Float16*)take((size_t)4 * 512 * 128 * 2);           // 512 KB
    _Float16* whh16  = (_Float16*)take((size_t)4 * 512 * 128 * 2);           // 512 KB
    _Float16* seqA   = (_Float16*)take((size_t)R2c * 128 * 2);               // 8.4 MB
    _Float16* hsA    = (_Float16*)take((size_t)R2c * 128 * 2);               // 8.4 MB
    _Float16* hsB    = (_Float16*)take((size_t)R2c * 128 * 2);               // 8.4 MB
    float*    xg     = (float*)take((size_t)R2c * 512 * 4);                  // 67 MB
    float*    stats  = (float*)take(1024);
    float*    c2     = (float*)take((size_t)4 * 32 * 128 * 4);

    auto prep16 = [&](const float* src, _Float16* dst, int R, int K, int OS, int KO) {
        int n = R * K;
        k_prep16s<<<(n + 255) / 256, 256, 0, stream>>>(src, dst, R, K, OS, KO);
    };

    // LSTM1 combined fp16 [Wih | Whh], row stride 128
    prep16(l1Wih0, wcomb1, 256, 32, 128, 0);
    prep16(l1Whh0, wcomb1, 256, 64, 128, 32);
    for (int l = 1; l < 4; ++l) {
        prep16(l1Wih + (l - 1) * 256 * 64, wcomb1 + (size_t)l * 256 * 128, 256, 64, 128, 0);
        prep16(l1Whh + (l - 1) * 256 * 64, wcomb1 + (size_t)l * 256 * 128, 256, 64, 128, 64);
    }
    // LSTM2 split: wih16 [4][512][128] (layer0 zero-padded), whh16 [4][512][128]
    hipMemsetAsync(wih16, 0, (size_t)512 * 128 * 2, stream);  // layer0 pad
    prep16(l2Wih0, wih16, 512, 64, 128, 0);
    for (int l = 1; l < 4; ++l)
        prep16(l2Wih + (l - 1) * 512 * 128, wih16 + (size_t)l * 512 * 128, 512, 128, 128, 0);
    prep16(l2Whh0, whh16, 512, 128, 128, 0);
    for (int l = 1; l < 4; ++l)
        prep16(l2Whh + (l - 1) * 512 * 128, whh16 + (size_t)l * 512 * 128, 512, 128, 128, 0);

    k_embed16<<<(NTc * EMBc + 255) / 256, 256, 0, stream>>>(atoms, embw, seq1f);

    for (int l = 0; l < 4; ++l) {
        const float* bp = (l == 0) ? l1b0 : l1b + (l - 1) * 256;
        if (l == 0)
            k_scan1f<32><<<Ntot / 32, 256, 0, stream>>>(seq1f, wcomb1, bp, dacc, 0, 1);
        else
            k_scan1f<64><<<Ntot / 32, 256, 0, stream>>>(seq1f, wcomb1 + (size_t)l * 256 * 128,
                                                        bp, dacc, 1, (l != 3) ? 1 : 0);
    }

    k_bn2_stats<<<32, 256, 0, stream>>>(lens, dacc, stats);
    k_bn2_apply<<<(R2c * 128 + 255) / 256, 256, 0, stream>>>(dacc, stats, lens, bn2g, bn2b, seqA);

    // LSTM2: per layer, xg GEMM then recurrence-only scan
    for (int l = 0; l < 4; ++l) {
        const _Float16* gin  = (l == 0) ? seqA : ((l & 1) ? hsA : hsB);
        _Float16*       hout = (l & 1) ? hsB : hsA;
        const float*    bp   = (l == 0) ? l2b0 : l2b + (l - 1) * 512;
        k_xg<<<R2c / 32, 256, 0, stream>>>(gin, wih16 + (size_t)l * 512 * 128, bp, xg);
        k_scan2g<<<8, 512, 0, stream>>>(xg, whh16 + (size_t)l * 512 * 128,
                                        hout, c2 + l * 4096, (l < 3) ? 1 : 0);
    }

    k_head<<<1, 256, 0, stream>>>(c2, bn3g, bn3b, w1, b1, w2, b2, w22, b22,
                                  w3, b3, w4, b4, w5, b5, out);

    (void)in_sizes; (void)n_in; (void)out_size; (void)ws_size;
}

// Round 12
// 3541.446 us; speedup vs baseline: 1.2944x; 1.1527x over previous
//
#include <hip/hip_runtime.h>

// Round 12: scan2h = 2x-unrolled scan (compile-time LDS parity), unconditional
// 2-deep xg prefetch (xg padded 2 steps), native xg layout [row][g*128+cell]
// (k_xg writes C-layout coalesced; scan reads 4 dwords w/ immediate offsets),
// writeH templated, c2 store hoisted out of the loop.

typedef _Float16 f16x8  __attribute__((ext_vector_type(8)));
typedef float    f32x4  __attribute__((ext_vector_type(4)));

#define DEVI static __device__ __forceinline__

constexpr int   T1c   = 20;
constexpr int   EMBc  = 32;
constexpr int   H1c   = 64;
constexpr int   LMAXc = 1024;
constexpr int   Ntot  = 24832;           // sum of lengths
constexpr int   NTc   = Ntot * T1c;      // 496640
constexpr int   R2c   = 32 * LMAXc;      // 32768
constexpr float EPSc  = 1e-5f;

DEVI float sigm(float x)   { return 1.f / (1.f + __expf(-x)); }
DEVI float tanhf_(float x) { return 1.f - 2.f / (1.f + __expf(2.f * x)); }

DEVI void barrier_lds() {                // barrier draining LDS only (not vmcnt)
    asm volatile("s_waitcnt lgkmcnt(0)\n\ts_barrier" ::: "memory");
}

// ---------------- weight prep: f32 -> fp16, row stride OS, col offset KO
__global__ void __launch_bounds__(256)
k_prep16s(const float* __restrict__ in, _Float16* __restrict__ out,
          int R, int K, int OS, int KO)
{
    int i = blockIdx.x * 256 + threadIdx.x;
    if (i >= R * K) return;
    int r = i / K, k = i - r * K;
    out[(size_t)r * OS + KO + k] = (_Float16)in[i];
}

// ---------------- embedding: x = embed_w[id] * id -> fp16 seq1 (row stride 64)
__global__ void __launch_bounds__(256)
k_embed16(const int* __restrict__ atoms, const float* __restrict__ ew,
          _Float16* __restrict__ s16)
{
    int i = blockIdx.x * 256 + threadIdx.x;
    if (i >= NTc * EMBc) return;
    int nt = i / EMBc, e = i - nt * EMBc;
    int id = atoms[nt];
    s16[(size_t)nt * H1c + e] = (_Float16)(ew[id * EMBc + e] * (float)id);
}

// ---------------- LSTM1 scan, single-term fp16 (unchanged)
template <int KIN>
__global__ void __launch_bounds__(256)
k_scan1f(_Float16* seq, const _Float16* __restrict__ W16,
         const float* __restrict__ bptr, float* __restrict__ dacc,
         int accum, int writeSeq)
{
    constexpr int KTOT = KIN + 64;
    constexpr int KCH  = KTOT / 32;
    constexpr int SX   = KTOT + 8;
    __shared__ alignas(16) _Float16 xh[32 * SX];

    const int tid  = threadIdx.x;
    const int lane = tid & 63;
    const int wv   = tid >> 6;
    const int l16  = lane & 15;
    const int quad = lane >> 4;
    const int n0   = blockIdx.x * 32;
    const int d    = wv * 16 + l16;

    float bias[4];
#pragma unroll
    for (int g = 0; g < 4; ++g) bias[g] = bptr[g * 64 + d];

    f16x8 wF[KCH][4];
#pragma unroll
    for (int kc = 0; kc < KCH; ++kc) {
        const int kb = kc * 32 + quad * 8;
#pragma unroll
        for (int g = 0; g < 4; ++g)
            wF[kc][g] = *(const f16x8*)&W16[(size_t)(g * 64 + d) * 128 + kb];
    }

    f32x4 c[2];
    c[0] = {1.f, 1.f, 1.f, 1.f};
    c[1] = {1.f, 1.f, 1.f, 1.f};

#pragma unroll
    for (int mt = 0; mt < 2; ++mt)
#pragma unroll
        for (int r = 0; r < 4; ++r)
            xh[(mt * 16 + quad * 4 + r) * SX + KIN + d] = (_Float16)1.0f;

#pragma unroll 1
    for (int t = 0; t < T1c; ++t) {
        for (int idx = tid; idx < 32 * (KIN / 8); idx += 256) {
            int s = idx / (KIN / 8), k8 = idx - s * (KIN / 8);
            *(f16x8*)&xh[s * SX + k8 * 8] =
                *(const f16x8*)&seq[((size_t)(n0 + s) * T1c + t) * H1c + k8 * 8];
        }
        __syncthreads();

        f32x4 acc[2][4];
#pragma unroll
        for (int mt = 0; mt < 2; ++mt)
#pragma unroll
            for (int g = 0; g < 4; ++g)
                acc[mt][g] = {bias[g], bias[g], bias[g], bias[g]};

#pragma unroll
        for (int kc = 0; kc < KCH; ++kc) {
            const int kb = kc * 32 + quad * 8;
            f16x8 ah[2];
#pragma unroll
            for (int mt = 0; mt < 2; ++mt)
                ah[mt] = *(const f16x8*)&xh[(mt * 16 + l16) * SX + kb];
#pragma unroll
            for (int g = 0; g < 4; ++g)
#pragma unroll
                for (int mt = 0; mt < 2; ++mt)
                    acc[mt][g] = __builtin_amdgcn_mfma_f32_16x16x32_f16(ah[mt], wF[kc][g], acc[mt][g], 0, 0, 0);
        }
        __syncthreads();

#pragma unroll
        for (int mt = 0; mt < 2; ++mt)
#pragma unroll
            for (int r = 0; r < 4; ++r) {
                float iv = sigm(acc[mt][0][r]);
                float fv = sigm(acc[mt][1][r]);
                float gv = tanhf_(acc[mt][2][r]);
                float ov = sigm(acc[mt][3][r]);
                float cv = fv * c[mt][r] + iv * gv;
                c[mt][r] = cv;
                float hv = ov * tanhf_(cv);
                _Float16 hf = (_Float16)hv;
                int s = mt * 16 + quad * 4 + r;
                xh[s * SX + KIN + d] = hf;
                if (writeSeq)
                    seq[((size_t)(n0 + s) * T1c + t) * H1c + d] = hf;
                if (t == T1c - 1) {
                    int o = (n0 + s) * H1c + d;
                    float val = 0.25f * (hv + cv);
                    if (accum) dacc[o] += val; else dacc[o] = val;
                }
            }
    }
}

// ---------------- BN2 stats
__global__ void __launch_bounds__(256)
k_bn2_stats(const int* __restrict__ lens, const float* __restrict__ dacc,
            float* __restrict__ stats)
{
    int b = blockIdx.x;
    int off = 0;
    for (int i = 0; i < b; ++i) off += lens[i];
    int len = lens[b];
    const float* base = dacc + (long)off * H1c;
    float s = 0.f, ss = 0.f;
    int total = len * H1c;
    for (int i = threadIdx.x; i < total; i += 256) { float v = base[i]; s += v; ss += v * v; }
    __shared__ float rs[256], rss[256];
    rs[threadIdx.x] = s; rss[threadIdx.x] = ss;
    __syncthreads();
    for (int st = 128; st > 0; st >>= 1) {
        if (threadIdx.x < st) { rs[threadIdx.x] += rs[threadIdx.x + st]; rss[threadIdx.x] += rss[threadIdx.x + st]; }
        __syncthreads();
    }
    if (threadIdx.x == 0) {
        float m = rs[0] / (float)(LMAXc * H1c);
        float v = rss[0] / (float)(LMAXc * H1c) - m * m;
        stats[b]      = m;
        stats[32 + b] = rsqrtf(fmaxf(v, 0.f) + EPSc);
        stats[64 + b] = (float)off;
    }
}

// ---------------- BN2 apply -> LSTM2 layer-0 input, fp16, rows (t*32+b) of 128
__global__ void __launch_bounds__(256)
k_bn2_apply(const float* __restrict__ dacc, const float* __restrict__ stats,
            const int* __restrict__ lens, const float* __restrict__ g,
            const float* __restrict__ bb, _Float16* __restrict__ outA)
{
    int i = blockIdx.x * 256 + threadIdx.x;
    if (i >= R2c * 128) return;
    int rr = i >> 7, k = i & 127;
    int b = rr >> 10, p = rr & 1023;
    float y = 0.f;
    if (k < H1c) {
        int off = (int)stats[64 + b];
        float x = (p < lens[b]) ? dacc[(off + p) * H1c + k] : 0.f;
        y = (x - stats[b]) * stats[32 + b] * g[b] + bb[b];
    }
    outA[(size_t)(p * 32 + b) * 128 + k] = (_Float16)y;
}

// ---------------- xg GEMM: xg[row][col] = bias[col] + Wih.x[row]  (native
// C-layout: col = g*128+cell; 16 consecutive 4B stores per inst = coalesced)
__global__ void __launch_bounds__(256)
k_xg(const _Float16* __restrict__ in,     // [32768][128] fp16
     const _Float16* __restrict__ Wih,    // [512][128] fp16 (gate-major rows)
     const float* __restrict__ bias,      // [512] gate-major
     float* __restrict__ xg)              // [32768][512] native
{
    constexpr int SX = 136;
    __shared__ alignas(16) _Float16 a[32 * SX];
    const int tid = threadIdx.x, lane = tid & 63, wv = tid >> 6;
    const int l16 = lane & 15, quad = lane >> 4;
    const int r0  = blockIdx.x * 32;

    for (int idx = tid; idx < 32 * 16; idx += 256) {
        int s = idx >> 4, k8 = idx & 15;
        *(f16x8*)&a[s * SX + k8 * 8] =
            *(const f16x8*)&in[(size_t)(r0 + s) * 128 + k8 * 8];
    }
    __syncthreads();

    f32x4 acc[2][8];
#pragma unroll
    for (int mt = 0; mt < 2; ++mt)
#pragma unroll
        for (int nt = 0; nt < 8; ++nt) {
            float bv = bias[wv * 128 + nt * 16 + l16];
            acc[mt][nt] = {bv, bv, bv, bv};
        }

#pragma unroll
    for (int kc = 0; kc < 4; ++kc) {
        const int kb = kc * 32 + quad * 8;
        f16x8 ah[2];
#pragma unroll
        for (int mt = 0; mt < 2; ++mt)
            ah[mt] = *(const f16x8*)&a[(mt * 16 + l16) * SX + kb];
#pragma unroll
        for (int nt = 0; nt < 8; ++nt) {
            f16x8 bh = *(const f16x8*)&Wih[(size_t)(wv * 128 + nt * 16 + l16) * 128 + kb];
#pragma unroll
            for (int mt = 0; mt < 2; ++mt)
                acc[mt][nt] = __builtin_amdgcn_mfma_f32_16x16x32_f16(ah[mt], bh, acc[mt][nt], 0, 0, 0);
        }
    }
#pragma unroll
    for (int mt = 0; mt < 2; ++mt)
#pragma unroll
        for (int nt = 0; nt < 8; ++nt)
#pragma unroll
            for (int r = 0; r < 4; ++r)
                xg[(size_t)(r0 + mt * 16 + quad * 4 + r) * 512 + wv * 128 + nt * 16 + l16]
                    = acc[mt][nt][r];
}

DEVI float qsel(f32x4 a, int quad) {     // a[quad] via cndmask
    float t01 = (quad & 1) ? a[1] : a[0];
    float t23 = (quad & 1) ? a[3] : a[2];
    return (quad & 2) ? t23 : t01;
}

// ---------------- LSTM2 recurrence-only scan (one layer per launch).
// 8 WGs x 4 samples; 512 thr = 8 waves (2/SIMD). Wave w owns cells
// [w*16,w*16+16); K=128 -> 16 MFMA/wave/step. 2x unrolled: compile-time LDS
// parity (immediate ds offsets). xg native layout: 4 dword loads at immediate
// offsets from one per-lane pointer; 2-step prefetch, no guards (xg padded).
template <int WRITEH>
__global__ void __launch_bounds__(512, 2)
k_scan2h(const float* __restrict__ xg,        // [32768+64][512] native (+pad)
         const _Float16* __restrict__ Whh,    // [512][128] fp16
         _Float16* __restrict__ hdst,         // h out (t*32+s rows) or unused
         float* __restrict__ c2out)           // [32][128] this layer
{
    constexpr int SH = 144;
    __shared__ alignas(16) _Float16 av[2][4 * SH];

    const int S0   = blockIdx.x * 4;
    const int tid  = threadIdx.x;
    const int lane = tid & 63;
    const int w    = tid >> 6;                // wave 0..7
    const int l16  = lane & 15, quad = lane >> 4;
    const int cell = w * 16 + l16;            // 0..127

    f16x8 wB[4][4];
#pragma unroll
    for (int g = 0; g < 4; ++g)
#pragma unroll
        for (int kc = 0; kc < 4; ++kc)
            wB[g][kc] = *(const f16x8*)&Whh[(size_t)(g * 128 + cell) * 128 + kc * 32 + quad * 8];

    const float* xq = xg + (size_t)(S0 + quad) * 512 + cell;   // +16384/step
    _Float16*    hp = hdst + (size_t)(S0 + quad) * 128 + cell; // +4096/step

    float cst = 1.f;
    av[1][quad * SH + cell] = (_Float16)1.0f;
    // prefetch steps 0 and 1 (4 gates each, immediate offsets)
    float xA0 = xq[0], xA1 = xq[128], xA2 = xq[256], xA3 = xq[384];
    xq += 16384;
    float xB0 = xq[0], xB1 = xq[128], xB2 = xq[256], xB3 = xq[384];
    xq += 16384;
    __syncthreads();

#pragma unroll 1
    for (int t = 0; t < LMAXc; t += 2) {
        // ======== even step: read parity 1, write parity 0, consume xA
        {
            float n0 = xq[0], n1 = xq[128], n2 = xq[256], n3 = xq[384]; // t+2
            f16x8 af[4];
#pragma unroll
            for (int kc = 0; kc < 4; ++kc)
                af[kc] = *(const f16x8*)&av[1][(l16 & 3) * SH + kc * 32 + quad * 8];
            f32x4 acc[4];
#pragma unroll
            for (int g = 0; g < 4; ++g) acc[g] = {0.f, 0.f, 0.f, 0.f};
#pragma unroll
            for (int kc = 0; kc < 4; ++kc)
#pragma unroll
                for (int g = 0; g < 4; ++g)
                    acc[g] = __builtin_amdgcn_mfma_f32_16x16x32_f16(af[kc], wB[g][kc], acc[g], 0, 0, 0);

            float gi = qsel(acc[0], quad) + xA0;
            float gf = qsel(acc[1], quad) + xA1;
            float gg = qsel(acc[2], quad) + xA2;
            float go = qsel(acc[3], quad) + xA3;
            float cv = sigm(gf) * cst + sigm(gi) * tanhf_(gg);
            cst = cv;
            float hv = sigm(go) * tanhf_(cv);
            _Float16 hf = (_Float16)hv;
            av[0][quad * SH + cell] = hf;
            if (WRITEH) { *hp = hf; hp += 4096; }
            xA0 = n0; xA1 = n1; xA2 = n2; xA3 = n3;
            barrier_lds();
        }
        // ======== odd step: read parity 0, write parity 1, consume xB
        {
            float n0 = xq[16384], n1 = xq[16384 + 128],
                  n2 = xq[16384 + 256], n3 = xq[16384 + 384];           // t+3
            f16x8 af[4];
#pragma unroll
            for (int kc = 0; kc < 4; ++kc)
                af[kc] = *(const f16x8*)&av[0][(l16 & 3) * SH + kc * 32 + quad * 8];
            f32x4 acc[4];
#pragma unroll
            for (int g = 0; g < 4; ++g) acc[g] = {0.f, 0.f, 0.f, 0.f};
#pragma unroll
            for (int kc = 0; kc < 4; ++kc)
#pragma unroll
                for (int g = 0; g < 4; ++g)
                    acc[g] = __builtin_amdgcn_mfma_f32_16x16x32_f16(af[kc], wB[g][kc], acc[g], 0, 0, 0);

            float gi = qsel(acc[0], quad) + xB0;
            float gf = qsel(acc[1], quad) + xB1;
            float gg = qsel(acc[2], quad) + xB2;
            float go = qsel(acc[3], quad) + xB3;
            float cv = sigm(gf) * cst + sigm(gi) * tanhf_(gg);
            cst = cv;
            float hv = sigm(go) * tanhf_(cv);
            _Float16 hf = (_Float16)hv;
            av[1][quad * SH + cell] = hf;
            if (WRITEH) { *hp = hf; hp += 4096; }
            xB0 = n0; xB1 = n1; xB2 = n2; xB3 = n3;
            xq += 2 * 16384;
            barrier_lds();
        }
    }
    c2out[(size_t)(S0 + quad) * 128 + cell] = 0.25f * cst;
}

// ---------------- head: BN3 + MLP + relu(sum), single WG fp32
DEVI void bn_rows_dev(float* X, int K, const float* g, const float* bb,
                      float* mv, int tid)
{
    __syncthreads();
    if (tid < 32) {
        float s = 0.f, ss = 0.f;
        const float* r = X + tid * K;
        for (int k = 0; k < K; ++k) { float v = r[k]; s += v; ss += v * v; }
        float m = s / (float)K;
        float vv = ss / (float)K - m * m;
        mv[tid]      = m;
        mv[32 + tid] = rsqrtf(fmaxf(vv, 0.f) + EPSc);
    }
    __syncthreads();
    for (int i = tid; i < 32 * K; i += 256) {
        int b = i / K;
        X[i] = (X[i] - mv[b]) * mv[32 + b] * g[b] + bb[b];
    }
    __syncthreads();
}

DEVI void lin_dev(const float* X, int K, const float* W, const float* bias,
                  int NO, float* Y, int relu, int tid)
{
    __syncthreads();
    for (int i = tid; i < 32 * NO; i += 256) {
        int b = i / NO, j = i - b * NO;
        float a = bias[j];
        const float* xr = X + b * K;
        const float* wr = W + j * K;
        for (int k = 0; k < K; ++k) a += xr[k] * wr[k];
        Y[i] = relu ? fmaxf(a, 0.f) : a;
    }
    __syncthreads();
}

__global__ void __launch_bounds__(256)
k_head(const float* __restrict__ c2, const float* __restrict__ g3, const float* __restrict__ bb3,
       const float* w1, const float* b1, const float* w2, const float* b2,
       const float* w22, const float* b22, const float* w3, const float* b3,
       const float* w4, const float* b4, const float* w5, const float* b5,
       float* __restrict__ out)
{
    __shared__ float A[32 * 128];
    __shared__ float Bf[32 * 128];
    __shared__ float mv[64];
    const int tid = threadIdx.x;

    for (int i = tid; i < 32 * 128; i += 256)
        A[i] = c2[i] + c2[4096 + i] + c2[8192 + i] + c2[12288 + i];
    bn_rows_dev(A, 128, g3, bb3, mv, tid);
    lin_dev(A, 128, w1, b1, 128, Bf, 1, tid);
    lin_dev(Bf, 128, w2, b2, 64, A, 1, tid);
    bn_rows_dev(A, 64, g3, bb3, mv, tid);
    lin_dev(A, 64, w22, b22, 64, Bf, 1, tid);
    lin_dev(Bf, 64, w3, b3, 32, A, 1, tid);
    lin_dev(A, 32, w4, b4, 32, Bf, 1, tid);
    lin_dev(Bf, 32, w5, b5, 16, A, 0, tid);
    if (tid < 32) {
        float s = 0.f;
        for (int j = 0; j < 16; ++j) s += A[tid * 16 + j];
        out[tid] = fmaxf(s, 0.f);
    }
}

// ---------------- host
extern "C" void kernel_launch(void* const* d_in, const int* in_sizes, int n_in,
                              void* d_out, int out_size, void* d_ws, size_t ws_size,
                              hipStream_t stream)
{
    const int*   atoms  = (const int*)d_in[0];
    const int*   lens   = (const int*)d_in[2];
    const float* embw   = (const float*)d_in[5];
    const float* l1Wih0 = (const float*)d_in[6];
    const float* l1Whh0 = (const float*)d_in[7];
    const float* l1b0   = (const float*)d_in[8];
    const float* l1Wih  = (const float*)d_in[9];
    const float* l1Whh  = (const float*)d_in[10];
    const float* l1b    = (const float*)d_in[11];
    const float* l2Wih0 = (const float*)d_in[12];
    const float* l2Whh0 = (const float*)d_in[13];
    const float* l2b0   = (const float*)d_in[14];
    const float* l2Wih  = (const float*)d_in[15];
    const float* l2Whh  = (const float*)d_in[16];
    const float* l2b    = (const float*)d_in[17];
    const float* bn2g   = (const float*)d_in[18];
    const float* bn2b   = (const float*)d_in[19];
    const float* bn3g   = (const float*)d_in[20];
    const float* bn3b   = (const float*)d_in[21];
    const float* w1  = (const float*)d_in[22]; const float* b1  = (const float*)d_in[23];
    const float* w2  = (const float*)d_in[24]; const float* b2  = (const float*)d_in[25];
    const float* w22 = (const float*)d_in[26]; const float* b22 = (const float*)d_in[27];
    const float* w3  = (const float*)d_in[28]; const float* b3  = (const float*)d_in[29];
    const float* w4  = (const float*)d_in[30]; const float* b4  = (const float*)d_in[31];
    const float* w5  = (const float*)d_in[32]; const float* b5  = (const float*)d_in[33];
    float* out = (float*)d_out;

    char* base = (char*)d_ws;
    size_t off = 0;
    auto take = [&](size_t bytes) -> char* {
        char* p = base + off;
        off = (off + bytes + 255) & ~(size_t)255;
        return p;
    };
    _Float16* seq1f  = (_Float16*)take((size_t)NTc * H1c * 2);               // 63.6 MB
    float*    dacc   = (float*)take((size_t)Ntot * H1c * 4);                 // 6.4 MB
    _Float16* wcomb1 = (_Float16*)take((size_t)4 * 256 * 128 * 2);           // 256 KB
    _Float16* wih16  = (_Float16*)take((size_t)4 * 512 * 128 * 2);           // 512 KB
    _Float16* whh16  = (_Float16*)take((size_t)4 * 512 * 128 * 2);           // 512 KB
    _Float16* seqA   = (_Float16*)take((size_t)R2c * 128 * 2);               // 8.4 MB
    _Float16* hsA    = (_Float16*)take((size_t)R2c * 128 * 2);               // 8.4 MB
    _Float16* hsB    = (_Float16*)take((size_t)R2c * 128 * 2);               // 8.4 MB
    float*    xg     = (float*)take((size_t)(R2c + 64) * 512 * 4);           // 67 MB + 2-step pad
    float*    stats  = (float*)take(1024);
    float*    c2     = (float*)take((size_t)4 * 32 * 128 * 4);

    auto prep16 = [&](const float* src, _Float16* dst, int R, int K, int OS, int KO) {
        int n = R * K;
        k_prep16s<<<(n + 255) / 256, 256, 0, stream>>>(src, dst, R, K, OS, KO);
    };

    // LSTM1 combined fp16 [Wih | Whh], row stride 128
    prep16(l1Wih0, wcomb1, 256, 32, 128, 0);
    prep16(l1Whh0, wcomb1, 256, 64, 128, 32);
    for (int l = 1; l < 4; ++l) {
        prep16(l1Wih + (l - 1) * 256 * 64, wcomb1 + (size_t)l * 256 * 128, 256, 64, 128, 0);
        prep16(l1Whh + (l - 1) * 256 * 64, wcomb1 + (size_t)l * 256 * 128, 256, 64, 128, 64);
    }
    // LSTM2 split: wih16 [4][512][128] (layer0 zero-padded), whh16 [4][512][128]
    hipMemsetAsync(wih16, 0, (size_t)512 * 128 * 2, stream);  // layer0 pad
    prep16(l2Wih0, wih16, 512, 64, 128, 0);
    for (int l = 1; l < 4; ++l)
        prep16(l2Wih + (l - 1) * 512 * 128, wih16 + (size_t)l * 512 * 128, 512, 128, 128, 0);
    prep16(l2Whh0, whh16, 512, 128, 128, 0);
    for (int l = 1; l < 4; ++l)
        prep16(l2Whh + (l - 1) * 512 * 128, whh16 + (size_t)l * 512 * 128, 512, 128, 128, 0);

    k_embed16<<<(NTc * EMBc + 255) / 256, 256, 0, stream>>>(atoms, embw, seq1f);

    for (int l = 0; l < 4; ++l) {
        const float* bp = (l == 0) ? l1b0 : l1b + (l - 1) * 256;
        if (l == 0)
            k_scan1f<32><<<Ntot / 32, 256, 0, stream>>>(seq1f, wcomb1, bp, dacc, 0, 1);
        else
            k_scan1f<64><<<Ntot / 32, 256, 0, stream>>>(seq1f, wcomb1 + (size_t)l * 256 * 128,
                                                        bp, dacc, 1, (l != 3) ? 1 : 0);
    }

    k_bn2_stats<<<32, 256, 0, stream>>>(lens, dacc, stats);
    k_bn2_apply<<<(R2c * 128 + 255) / 256, 256, 0, stream>>>(dacc, stats, lens, bn2g, bn2b, seqA);

    // LSTM2: per layer, xg GEMM then recurrence-only scan
    for (int l = 0; l < 4; ++l) {
        const _Float16* gin  = (l == 0) ? seqA : ((l & 1) ? hsA : hsB);
        _Float16*       hout = (l & 1) ? hsB : hsA;
        const float*    bp   = (l == 0) ? l2b0 : l2b + (l - 1) * 512;
        k_xg<<<R2c / 32, 256, 0, stream>>>(gin, wih16 + (size_t)l * 512 * 128, bp, xg);
        if (l < 3)
            k_scan2h<1><<<8, 512, 0, stream>>>(xg, whh16 + (size_t)l * 512 * 128,
                                               hout, c2 + l * 4096);
        else
            k_scan2h<0><<<8, 512, 0, stream>>>(xg, whh16 + (size_t)l * 512 * 128,
                                               hout, c2 + l * 4096);
    }

    k_head<<<1, 256, 0, stream>>>(c2, bn3g, bn3b, w1, b1, w2, b2, w22, b22,
                                  w3, b3, w4, b4, w5, b5, out);

    (void)in_sizes; (void)n_in; (void)out_size; (void)ws_size;
}

// Round 13
// 3491.889 us; speedup vs baseline: 1.3128x; 1.0142x over previous
//
#include <hip/hip_runtime.h>

// Round 13: shrink the non-scan tail.
//  - k_scan1all: ALL of LSTM1 in one kernel: embed fused (ew+atoms in LDS),
//    4 layers looped in-WG (deps are WG-private: same 32 samples), layer-0
//    zero-padded to K=64 for a uniform K=128 body, dacc reg-accumulated.
//  - k_prepw1/k_prepw2: all 17 weight preps + memset -> 2 kernels.
//  - LSTM2 (k_xg + k_scan2h) untouched from R12 (637 us/layer, 0 conflicts).

typedef _Float16 f16x8  __attribute__((ext_vector_type(8)));
typedef float    f32x4  __attribute__((ext_vector_type(4)));

#define DEVI static __device__ __forceinline__

constexpr int   T1c   = 20;
constexpr int   EMBc  = 32;
constexpr int   H1c   = 64;
constexpr int   LMAXc = 1024;
constexpr int   VOCABc= 85;
constexpr int   Ntot  = 24832;           // sum of lengths
constexpr int   NTc   = Ntot * T1c;      // 496640
constexpr int   R2c   = 32 * LMAXc;      // 32768
constexpr float EPSc  = 1e-5f;

DEVI float sigm(float x)   { return 1.f / (1.f + __expf(-x)); }
DEVI float tanhf_(float x) { return 1.f - 2.f / (1.f + __expf(2.f * x)); }

DEVI void barrier_lds() {                // barrier draining LDS only (not vmcnt)
    asm volatile("s_waitcnt lgkmcnt(0)\n\ts_barrier" ::: "memory");
}
DEVI void drain_vmem() {
    asm volatile("s_waitcnt vmcnt(0)" ::: "memory");
}

// ---------------- prep: LSTM1 combined fp16 [4][256][128] = [Wih|pad|Whh]
__global__ void __launch_bounds__(256)
k_prepw1(const float* __restrict__ Wih0, const float* __restrict__ Whh0,
         const float* __restrict__ WihS, const float* __restrict__ WhhS,
         _Float16* __restrict__ out)
{
    int i = blockIdx.x * 256 + threadIdx.x;
    if (i >= 4 * 256 * 128) return;
    int l = i >> 15, rem = i & 32767, r = rem >> 7, k = rem & 127;
    float v;
    if (l == 0) {
        if (k < 32)      v = Wih0[r * 32 + k];
        else if (k < 64) v = 0.f;
        else             v = Whh0[r * 64 + (k - 64)];
    } else {
        if (k < 64)      v = WihS[((l - 1) * 256 + r) * 64 + k];
        else             v = WhhS[((l - 1) * 256 + r) * 64 + (k - 64)];
    }
    out[i] = (_Float16)v;
}

// ---------------- prep: LSTM2 wih16 [4][512][128] (l0 zero-padded) + whh16
__global__ void __launch_bounds__(256)
k_prepw2(const float* __restrict__ Wih0, const float* __restrict__ WihS,
         const float* __restrict__ Whh0, const float* __restrict__ WhhS,
         _Float16* __restrict__ wih, _Float16* __restrict__ whh)
{
    int i = blockIdx.x * 256 + threadIdx.x;
    if (i >= 2 * 4 * 512 * 128) return;
    int half = i >> 18, rem = i & 262143;
    int l = rem >> 16, r = (rem >> 7) & 511, k = rem & 127;
    if (half == 0) {
        float v = (l == 0) ? ((k < 64) ? Wih0[r * 64 + k] : 0.f)
                           : WihS[((l - 1) * 512 + r) * 128 + k];
        wih[rem] = (_Float16)v;
    } else {
        float v = (l == 0) ? Whh0[r * 128 + k]
                           : WhhS[((l - 1) * 512 + r) * 128 + k];
        whh[rem] = (_Float16)v;
    }
}

// ---------------- LSTM1: embed + 4 layers fused, one kernel. 32 samples/WG,
// 256 thr = 4 waves. Uniform K=128 body ([x(64, l0 zero-padded)|h(64)]).
// Inter-layer seq dependency is WG-private -> vmcnt drain + barrier.
__global__ void __launch_bounds__(256)
k_scan1all(const int* __restrict__ atoms, const float* __restrict__ ew,
           const _Float16* __restrict__ W16all,
           const float* __restrict__ b0, const float* __restrict__ bS,
           _Float16* __restrict__ seq, float* __restrict__ dacc)
{
    constexpr int SX = 136;
    __shared__ alignas(16) _Float16 xh[32 * SX];     // 8.7 KB
    __shared__ float ewl[VOCABc * EMBc];             // 10.9 KB
    __shared__ int   aidl[32 * T1c];                 // 2.5 KB

    const int tid  = threadIdx.x;
    const int lane = tid & 63;
    const int wv   = tid >> 6;
    const int l16  = lane & 15;
    const int quad = lane >> 4;
    const int n0   = blockIdx.x * 32;
    const int d    = wv * 16 + l16;

    for (int i = tid; i < VOCABc * EMBc; i += 256) ewl[i] = ew[i];
    for (int i = tid; i < 32 * T1c; i += 256) aidl[i] = atoms[n0 * T1c + i];

    float daccv[2][4];
#pragma unroll
    for (int mt = 0; mt < 2; ++mt)
#pragma unroll
        for (int r = 0; r < 4; ++r) daccv[mt][r] = 0.f;

    __syncthreads();

#pragma unroll 1
    for (int l = 0; l < 4; ++l) {
        const _Float16* W16  = W16all + (size_t)l * 256 * 128;
        const float*    bptr = (l == 0) ? b0 : bS + (l - 1) * 256;

        float bias[4];
#pragma unroll
        for (int g = 0; g < 4; ++g) bias[g] = bptr[g * 64 + d];

        f16x8 wF[4][4];
#pragma unroll
        for (int kc = 0; kc < 4; ++kc) {
            const int kb = kc * 32 + quad * 8;
#pragma unroll
            for (int g = 0; g < 4; ++g)
                wF[kc][g] = *(const f16x8*)&W16[(size_t)(g * 64 + d) * 128 + kb];
        }

        f32x4 c[2];
        c[0] = {1.f, 1.f, 1.f, 1.f};
        c[1] = {1.f, 1.f, 1.f, 1.f};

        drain_vmem();            // prev layer's seq stores complete (same CU)
        __syncthreads();

        // h(t=-1) = 1; layer 0: zero x cols [32,64) once (zero weights there)
#pragma unroll
        for (int mt = 0; mt < 2; ++mt)
#pragma unroll
            for (int r = 0; r < 4; ++r)
                xh[(mt * 16 + quad * 4 + r) * SX + 64 + d] = (_Float16)1.0f;
        if (l == 0)
            for (int idx = tid; idx < 32 * 32; idx += 256) {
                int s = idx >> 5, e = idx & 31;
                xh[s * SX + 32 + e] = (_Float16)0.f;
            }

#pragma unroll 1
        for (int t = 0; t < T1c; ++t) {
            if (l == 0) {
                for (int idx = tid; idx < 32 * 32; idx += 256) {
                    int s = idx >> 5, e = idx & 31;
                    int id = aidl[s * T1c + t];
                    xh[s * SX + e] = (_Float16)(ewl[id * EMBc + e] * (float)id);
                }
            } else {
                for (int idx = tid; idx < 32 * 8; idx += 256) {
                    int s = idx >> 3, k8 = idx & 7;
                    *(f16x8*)&xh[s * SX + k8 * 8] =
                        *(const f16x8*)&seq[((size_t)(n0 + s) * T1c + t) * H1c + k8 * 8];
                }
            }
            __syncthreads();

            f32x4 acc[2][4];
#pragma unroll
            for (int mt = 0; mt < 2; ++mt)
#pragma unroll
                for (int g = 0; g < 4; ++g)
                    acc[mt][g] = {bias[g], bias[g], bias[g], bias[g]};

#pragma unroll
            for (int kc = 0; kc < 4; ++kc) {
                const int kb = kc * 32 + quad * 8;
                f16x8 ah[2];
#pragma unroll
                for (int mt = 0; mt < 2; ++mt)
                    ah[mt] = *(const f16x8*)&xh[(mt * 16 + l16) * SX + kb];
#pragma unroll
                for (int g = 0; g < 4; ++g)
#pragma unroll
                    for (int mt = 0; mt < 2; ++mt)
                        acc[mt][g] = __builtin_amdgcn_mfma_f32_16x16x32_f16(ah[mt], wF[kc][g], acc[mt][g], 0, 0, 0);
            }
            __syncthreads();

#pragma unroll
            for (int mt = 0; mt < 2; ++mt)
#pragma unroll
                for (int r = 0; r < 4; ++r) {
                    float iv = sigm(acc[mt][0][r]);
                    float fv = sigm(acc[mt][1][r]);
                    float gv = tanhf_(acc[mt][2][r]);
                    float ov = sigm(acc[mt][3][r]);
                    float cv = fv * c[mt][r] + iv * gv;
                    c[mt][r] = cv;
                    float hv = ov * tanhf_(cv);
                    _Float16 hf = (_Float16)hv;
                    int s = mt * 16 + quad * 4 + r;
                    xh[s * SX + 64 + d] = hf;
                    if (l < 3)
                        seq[((size_t)(n0 + s) * T1c + t) * H1c + d] = hf;
                    if (t == T1c - 1)
                        daccv[mt][r] += 0.25f * (hv + cv);
                }
        }
    }
#pragma unroll
    for (int mt = 0; mt < 2; ++mt)
#pragma unroll
        for (int r = 0; r < 4; ++r) {
            int s = mt * 16 + quad * 4 + r;
            dacc[(size_t)(n0 + s) * H1c + d] = daccv[mt][r];
        }
}

// ---------------- BN2 stats
__global__ void __launch_bounds__(256)
k_bn2_stats(const int* __restrict__ lens, const float* __restrict__ dacc,
            float* __restrict__ stats)
{
    int b = blockIdx.x;
    int off = 0;
    for (int i = 0; i < b; ++i) off += lens[i];
    int len = lens[b];
    const float* base = dacc + (long)off * H1c;
    float s = 0.f, ss = 0.f;
    int total = len * H1c;
    for (int i = threadIdx.x; i < total; i += 256) { float v = base[i]; s += v; ss += v * v; }
    __shared__ float rs[256], rss[256];
    rs[threadIdx.x] = s; rss[threadIdx.x] = ss;
    __syncthreads();
    for (int st = 128; st > 0; st >>= 1) {
        if (threadIdx.x < st) { rs[threadIdx.x] += rs[threadIdx.x + st]; rss[threadIdx.x] += rss[threadIdx.x + st]; }
        __syncthreads();
    }
    if (threadIdx.x == 0) {
        float m = rs[0] / (float)(LMAXc * H1c);
        float v = rss[0] / (float)(LMAXc * H1c) - m * m;
        stats[b]      = m;
        stats[32 + b] = rsqrtf(fmaxf(v, 0.f) + EPSc);
        stats[64 + b] = (float)off;
    }
}

// ---------------- BN2 apply -> LSTM2 layer-0 input, fp16, rows (t*32+b) of 128
__global__ void __launch_bounds__(256)
k_bn2_apply(const float* __restrict__ dacc, const float* __restrict__ stats,
            const int* __restrict__ lens, const float* __restrict__ g,
            const float* __restrict__ bb, _Float16* __restrict__ outA)
{
    int i = blockIdx.x * 256 + threadIdx.x;
    if (i >= R2c * 128) return;
    int rr = i >> 7, k = i & 127;
    int b = rr >> 10, p = rr & 1023;
    float y = 0.f;
    if (k < H1c) {
        int off = (int)stats[64 + b];
        float x = (p < lens[b]) ? dacc[(off + p) * H1c + k] : 0.f;
        y = (x - stats[b]) * stats[32 + b] * g[b] + bb[b];
    }
    outA[(size_t)(p * 32 + b) * 128 + k] = (_Float16)y;
}

// ---------------- xg GEMM: xg[row][col] = bias[col] + Wih.x[row]  (native
// C-layout: col = g*128+cell; 16 consecutive 4B stores per inst = coalesced)
__global__ void __launch_bounds__(256)
k_xg(const _Float16* __restrict__ in,     // [32768][128] fp16
     const _Float16* __restrict__ Wih,    // [512][128] fp16 (gate-major rows)
     const float* __restrict__ bias,      // [512] gate-major
     float* __restrict__ xg)              // [32768][512] native
{
    constexpr int SX = 136;
    __shared__ alignas(16) _Float16 a[32 * SX];
    const int tid = threadIdx.x, lane = tid & 63, wv = tid >> 6;
    const int l16 = lane & 15, quad = lane >> 4;
    const int r0  = blockIdx.x * 32;

    for (int idx = tid; idx < 32 * 16; idx += 256) {
        int s = idx >> 4, k8 = idx & 15;
        *(f16x8*)&a[s * SX + k8 * 8] =
            *(const f16x8*)&in[(size_t)(r0 + s) * 128 + k8 * 8];
    }
    __syncthreads();

    f32x4 acc[2][8];
#pragma unroll
    for (int mt = 0; mt < 2; ++mt)
#pragma unroll
        for (int nt = 0; nt < 8; ++nt) {
            float bv = bias[wv * 128 + nt * 16 + l16];
            acc[mt][nt] = {bv, bv, bv, bv};
        }

#pragma unroll
    for (int kc = 0; kc < 4; ++kc) {
        const int kb = kc * 32 + quad * 8;
        f16x8 ah[2];
#pragma unroll
        for (int mt = 0; mt < 2; ++mt)
            ah[mt] = *(const f16x8*)&a[(mt * 16 + l16) * SX + kb];
#pragma unroll
        for (int nt = 0; nt < 8; ++nt) {
            f16x8 bh = *(const f16x8*)&Wih[(size_t)(wv * 128 + nt * 16 + l16) * 128 + kb];
#pragma unroll
            for (int mt = 0; mt < 2; ++mt)
                acc[mt][nt] = __builtin_amdgcn_mfma_f32_16x16x32_f16(ah[mt], bh, acc[mt][nt], 0, 0, 0);
        }
    }
#pragma unroll
    for (int mt = 0; mt < 2; ++mt)
#pragma unroll
        for (int nt = 0; nt < 8; ++nt)
#pragma unroll
            for (int r = 0; r < 4; ++r)
                xg[(size_t)(r0 + mt * 16 + quad * 4 + r) * 512 + wv * 128 + nt * 16 + l16]
                    = acc[mt][nt][r];
}

DEVI float qsel(f32x4 a, int quad) {     // a[quad] via cndmask
    float t01 = (quad & 1) ? a[1] : a[0];
    float t23 = (quad & 1) ? a[3] : a[2];
    return (quad & 2) ? t23 : t01;
}

// ---------------- LSTM2 recurrence-only scan (one layer per launch) - as R12.
template <int WRITEH>
__global__ void __launch_bounds__(512, 2)
k_scan2h(const float* __restrict__ xg,        // [32768+64][512] native (+pad)
         const _Float16* __restrict__ Whh,    // [512][128] fp16
         _Float16* __restrict__ hdst,         // h out (t*32+s rows) or unused
         float* __restrict__ c2out)           // [32][128] this layer
{
    constexpr int SH = 144;
    __shared__ alignas(16) _Float16 av[2][4 * SH];

    const int S0   = blockIdx.x * 4;
    const int tid  = threadIdx.x;
    const int lane = tid & 63;
    const int w    = tid >> 6;                // wave 0..7
    const int l16  = lane & 15, quad = lane >> 4;
    const int cell = w * 16 + l16;            // 0..127

    f16x8 wB[4][4];
#pragma unroll
    for (int g = 0; g < 4; ++g)
#pragma unroll
        for (int kc = 0; kc < 4; ++kc)
            wB[g][kc] = *(const f16x8*)&Whh[(size_t)(g * 128 + cell) * 128 + kc * 32 + quad * 8];

    const float* xq = xg + (size_t)(S0 + quad) * 512 + cell;   // +16384/step
    _Float16*    hp = hdst + (size_t)(S0 + quad) * 128 + cell; // +4096/step

    float cst = 1.f;
    av[1][quad * SH + cell] = (_Float16)1.0f;
    float xA0 = xq[0], xA1 = xq[128], xA2 = xq[256], xA3 = xq[384];
    xq += 16384;
    float xB0 = xq[0], xB1 = xq[128], xB2 = xq[256], xB3 = xq[384];
    xq += 16384;
    __syncthreads();

#pragma unroll 1
    for (int t = 0; t < LMAXc; t += 2) {
        {   // even step: read parity 1, write parity 0, consume xA
            float n0 = xq[0], n1 = xq[128], n2 = xq[256], n3 = xq[384];
            f16x8 af[4];
#pragma unroll
            for (int kc = 0; kc < 4; ++kc)
                af[kc] = *(const f16x8*)&av[1][(l16 & 3) * SH + kc * 32 + quad * 8];
            f32x4 acc[4];
#pragma unroll
            for (int g = 0; g < 4; ++g) acc[g] = {0.f, 0.f, 0.f, 0.f};
#pragma unroll
            for (int kc = 0; kc < 4; ++kc)
#pragma unroll
                for (int g = 0; g < 4; ++g)
                    acc[g] = __builtin_amdgcn_mfma_f32_16x16x32_f16(af[kc], wB[g][kc], acc[g], 0, 0, 0);

            float gi = qsel(acc[0], quad) + xA0;
            float gf = qsel(acc[1], quad) + xA1;
            float gg = qsel(acc[2], quad) + xA2;
            float go = qsel(acc[3], quad) + xA3;
            float cv = sigm(gf) * cst + sigm(gi) * tanhf_(gg);
            cst = cv;
            float hv = sigm(go) * tanhf_(cv);
            _Float16 hf = (_Float16)hv;
            av[0][quad * SH + cell] = hf;
            if (WRITEH) { *hp = hf; hp += 4096; }
            xA0 = n0; xA1 = n1; xA2 = n2; xA3 = n3;
            barrier_lds();
        }
        {   // odd step: read parity 0, write parity 1, consume xB
            float n0 = xq[16384], n1 = xq[16384 + 128],
                  n2 = xq[16384 + 256], n3 = xq[16384 + 384];
            f16x8 af[4];
#pragma unroll
            for (int kc = 0; kc < 4; ++kc)
                af[kc] = *(const f16x8*)&av[0][(l16 & 3) * SH + kc * 32 + quad * 8];
            f32x4 acc[4];
#pragma unroll
            for (int g = 0; g < 4; ++g) acc[g] = {0.f, 0.f, 0.f, 0.f};
#pragma unroll
            for (int kc = 0; kc < 4; ++kc)
#pragma unroll
                for (int g = 0; g < 4; ++g)
                    acc[g] = __builtin_amdgcn_mfma_f32_16x16x32_f16(af[kc], wB[g][kc], acc[g], 0, 0, 0);

            float gi = qsel(acc[0], quad) + xB0;
            float gf = qsel(acc[1], quad) + xB1;
            float gg = qsel(acc[2], quad) + xB2;
            float go = qsel(acc[3], quad) + xB3;
            float cv = sigm(gf) * cst + sigm(gi) * tanhf_(gg);
            cst = cv;
            float hv = sigm(go) * tanhf_(cv);
            _Float16 hf = (_Float16)hv;
            av[1][quad * SH + cell] = hf;
            if (WRITEH) { *hp = hf; hp += 4096; }
            xB0 = n0; xB1 = n1; xB2 = n2; xB3 = n3;
            xq += 2 * 16384;
            barrier_lds();
        }
    }
    c2out[(size_t)(S0 + quad) * 128 + cell] = 0.25f * cst;
}

// ---------------- head: BN3 + MLP + relu(sum), single WG fp32
DEVI void bn_rows_dev(float* X, int K, const float* g, const float* bb,
                      float* mv, int tid)
{
    __syncthreads();
    if (tid < 32) {
        float s = 0.f, ss = 0.f;
        const float* r = X + tid * K;
        for (int k = 0; k < K; ++k) { float v = r[k]; s += v; ss += v * v; }
        float m = s / (float)K;
        float vv = ss / (float)K - m * m;
        mv[tid]      = m;
        mv[32 + tid] = rsqrtf(fmaxf(vv, 0.f) + EPSc);
    }
    __syncthreads();
    for (int i = tid; i < 32 * K; i += 256) {
        int b = i / K;
        X[i] = (X[i] - mv[b]) * mv[32 + b] * g[b] + bb[b];
    }
    __syncthreads();
}

DEVI void lin_dev(const float* X, int K, const float* W, const float* bias,
                  int NO, float* Y, int relu, int tid)
{
    __syncthreads();
    for (int i = tid; i < 32 * NO; i += 256) {
        int b = i / NO, j = i - b * NO;
        float a = bias[j];
        const float* xr = X + b * K;
        const float* wr = W + j * K;
        for (int k = 0; k < K; ++k) a += xr[k] * wr[k];
        Y[i] = relu ? fmaxf(a, 0.f) : a;
    }
    __syncthreads();
}

__global__ void __launch_bounds__(256)
k_head(const float* __restrict__ c2, const float* __restrict__ g3, const float* __restrict__ bb3,
       const float* w1, const float* b1, const float* w2, const float* b2,
       const float* w22, const float* b22, const float* w3, const float* b3,
       const float* w4, const float* b4, const float* w5, const float* b5,
       float* __restrict__ out)
{
    __shared__ float A[32 * 128];
    __shared__ float Bf[32 * 128];
    __shared__ float mv[64];
    const int tid = threadIdx.x;

    for (int i = tid; i < 32 * 128; i += 256)
        A[i] = c2[i] + c2[4096 + i] + c2[8192 + i] + c2[12288 + i];
    bn_rows_dev(A, 128, g3, bb3, mv, tid);
    lin_dev(A, 128, w1, b1, 128, Bf, 1, tid);
    lin_dev(Bf, 128, w2, b2, 64, A, 1, tid);
    bn_rows_dev(A, 64, g3, bb3, mv, tid);
    lin_dev(A, 64, w22, b22, 64, Bf, 1, tid);
    lin_dev(Bf, 64, w3, b3, 32, A, 1, tid);
    lin_dev(A, 32, w4, b4, 32, Bf, 1, tid);
    lin_dev(Bf, 32, w5, b5, 16, A, 0, tid);
    if (tid < 32) {
        float s = 0.f;
        for (int j = 0; j < 16; ++j) s += A[tid * 16 + j];
        out[tid] = fmaxf(s, 0.f);
    }
}

// ---------------- host
extern "C" void kernel_launch(void* const* d_in, const int* in_sizes, int n_in,
                              void* d_out, int out_size, void* d_ws, size_t ws_size,
                              hipStream_t stream)
{
    const int*   atoms  = (const int*)d_in[0];
    const int*   lens   = (const int*)d_in[2];
    const float* embw   = (const float*)d_in[5];
    const float* l1Wih0 = (const float*)d_in[6];
    const float* l1Whh0 = (const float*)d_in[7];
    const float* l1b0   = (const float*)d_in[8];
    const float* l1Wih  = (const float*)d_in[9];
    const float* l1Whh  = (const float*)d_in[10];
    const float* l1b    = (const float*)d_in[11];
    const float* l2Wih0 = (const float*)d_in[12];
    const float* l2Whh0 = (const float*)d_in[13];
    const float* l2b0   = (const float*)d_in[14];
    const float* l2Wih  = (const float*)d_in[15];
    const float* l2Whh  = (const float*)d_in[16];
    const float* l2b    = (const float*)d_in[17];
    const float* bn2g   = (const float*)d_in[18];
    const float* bn2b   = (const float*)d_in[19];
    const float* bn3g   = (const float*)d_in[20];
    const float* bn3b   = (const float*)d_in[21];
    const float* w1  = (const float*)d_in[22]; const float* b1  = (const float*)d_in[23];
    const float* w2  = (const float*)d_in[24]; const float* b2  = (const float*)d_in[25];
    const float* w22 = (const float*)d_in[26]; const float* b22 = (const float*)d_in[27];
    const float* w3  = (const float*)d_in[28]; const float* b3  = (const float*)d_in[29];
    const float* w4  = (const float*)d_in[30]; const float* b4  = (const float*)d_in[31];
    const float* w5  = (const float*)d_in[32]; const float* b5  = (const float*)d_in[33];
    float* out = (float*)d_out;

    char* base = (char*)d_ws;
    size_t off = 0;
    auto take = [&](size_t bytes) -> char* {
        char* p = base + off;
        off = (off + bytes + 255) & ~(size_t)255;
        return p;
    };
    _Float16* seq1f  = (_Float16*)take((size_t)NTc * H1c * 2);               // 63.6 MB
    float*    dacc   = (float*)take((size_t)Ntot * H1c * 4);                 // 6.4 MB
    _Float16* wcomb1 = (_Float16*)take((size_t)4 * 256 * 128 * 2);           // 256 KB
    _Float16* wih16  = (_Float16*)take((size_t)4 * 512 * 128 * 2);           // 512 KB
    _Float16* whh16  = (_Float16*)take((size_t)4 * 512 * 128 * 2);           // 512 KB
    _Float16* seqA   = (_Float16*)take((size_t)R2c * 128 * 2);               // 8.4 MB
    _Float16* hsA    = (_Float16*)take((size_t)R2c * 128 * 2);               // 8.4 MB
    _Float16* hsB    = (_Float16*)take((size_t)R2c * 128 * 2);               // 8.4 MB
    float*    xg     = (float*)take((size_t)(R2c + 64) * 512 * 4);           // 67 MB + pad
    float*    stats  = (float*)take(1024);
    float*    c2     = (float*)take((size_t)4 * 32 * 128 * 4);

    // weight preps: 2 kernels
    k_prepw1<<<(4 * 256 * 128 + 255) / 256, 256, 0, stream>>>(l1Wih0, l1Whh0, l1Wih, l1Whh, wcomb1);
    k_prepw2<<<(2 * 4 * 512 * 128 + 255) / 256, 256, 0, stream>>>(l2Wih0, l2Wih, l2Whh0, l2Whh, wih16, whh16);

    // LSTM1: embed + 4 layers fused
    k_scan1all<<<Ntot / 32, 256, 0, stream>>>(atoms, embw, wcomb1, l1b0, l1b, seq1f, dacc);

    k_bn2_stats<<<32, 256, 0, stream>>>(lens, dacc, stats);
    k_bn2_apply<<<(R2c * 128 + 255) / 256, 256, 0, stream>>>(dacc, stats, lens, bn2g, bn2b, seqA);

    // LSTM2: per layer, xg GEMM then recurrence-only scan
    for (int l = 0; l < 4; ++l) {
        const _Float16* gin  = (l == 0) ? seqA : ((l & 1) ? hsA : hsB);
        _Float16*       hout = (l & 1) ? hsB : hsA;
        const float*    bp   = (l == 0) ? l2b0 : l2b + (l - 1) * 512;
        k_xg<<<R2c / 32, 256, 0, stream>>>(gin, wih16 + (size_t)l * 512 * 128, bp, xg);
        if (l < 3)
            k_scan2h<1><<<8, 512, 0, stream>>>(xg, whh16 + (size_t)l * 512 * 128,
                                               hout, c2 + l * 4096);
        else
            k_scan2h<0><<<8, 512, 0, stream>>>(xg, whh16 + (size_t)l * 512 * 128,
                                               hout, c2 + l * 4096);
    }

    k_head<<<1, 256, 0, stream>>>(c2, bn3g, bn3b, w1, b1, w2, b2, w22, b22,
                                  w3, b3, w4, b4, w5, b5, out);

    (void)in_sizes; (void)n_in; (void)out_size; (void)ws_size;
}